// Round 9
// baseline (292.321 us; speedup 1.0000x reference)
//
#include <hip/hip_runtime.h>

#define MU 5
static constexpr int Hh = 1024, Ww = 1024, Bb = 8;
static constexpr int NPIX = Bb * Hh * Ww;
static constexpr int TPB = 256;
static constexpr int SOBEL_BLOCKS = NPIX / 4 / TPB;     // 8192 (4 px/thread)

// fused V+H tile
static constexpr int TX = 64, TY = 32;
static constexpr int VW = TX + 2 * MU;        // 74 staged cols
static constexpr int ER = TY + 2 * MU;        // 42 E rows
static constexpr int EP = 75;                 // ODD pitch: bank-conflict-free
static constexpr int FBLK = (Ww / TX) * (Hh / TY) * Bb;   // 4096

__device__ __forceinline__ float rcp_fast(float x) { return __builtin_amdgcn_rcpf(x); }
__device__ __forceinline__ float rsq_fast(float x) { return __builtin_amdgcn_rsqf(x); }

// ---- Sobel v2: 4 px per thread along a row; float4 + 2 edge scalars ----
__global__ __launch_bounds__(TPB) void sobel_kernel(
        const float* __restrict__ in, float2* __restrict__ tang,
        float* __restrict__ mag, float* __restrict__ partials) {
    int id = blockIdx.x * TPB + threadIdx.x;
    int xq = id & (Ww / 4 - 1);
    int x0 = xq * 4;
    int y  = (id >> 8) & (Hh - 1);
    int b  = id >> 18;
    const float* p = in + ((size_t)b << 20);

    float c[3][6];
    #pragma unroll
    for (int r = 0; r < 3; ++r) {
        int yy = y - 1 + r;
        bool okr = (yy >= 0) && (yy < Hh);
        const float* row = p + (okr ? yy : 0) * Ww;
        float4 v = okr ? *(const float4*)(row + x0) : make_float4(0.f, 0.f, 0.f, 0.f);
        c[r][1] = v.x; c[r][2] = v.y; c[r][3] = v.z; c[r][4] = v.w;
        c[r][0] = (okr && x0 > 0)      ? row[x0 - 1] : 0.0f;
        c[r][5] = (okr && x0 + 4 < Ww) ? row[x0 + 4] : 0.0f;
    }

    float S[6], D[6];
    #pragma unroll
    for (int cc = 0; cc < 6; ++cc) {
        S[cc] = c[0][cc] + 2.0f * c[1][cc] + c[2][cc];
        D[cc] = c[2][cc] - c[0][cc];
    }

    float2 tg[4];
    float  mg[4];
    float vmax = 0.0f;
    #pragma unroll
    for (int k = 0; k < 4; ++k) {
        float gx = S[k + 2] - S[k];
        float gy = D[k] + 2.0f * D[k + 1] + D[k + 2];
        float g2 = gx * gx + gy * gy;
        float irs = rsq_fast(g2);
        float m   = (g2 > 0.0f) ? g2 * irs : 0.0f;   // sqrt
        float inv = (g2 > 0.0f) ? irs : 1.0f;        // 1/sqrt
        mg[k] = m;
        tg[k] = make_float2(-gy * inv, gx * inv);
        vmax = fmaxf(vmax, m);
    }

    int idx = (b << 20) + y * Ww + x0;
    *(float4*)&mag[idx] = make_float4(mg[0], mg[1], mg[2], mg[3]);
    float4* tp = (float4*)&tang[idx];
    tp[0] = make_float4(tg[0].x, tg[0].y, tg[1].x, tg[1].y);
    tp[1] = make_float4(tg[2].x, tg[2].y, tg[3].x, tg[3].y);

    #pragma unroll
    for (int off = 32; off; off >>= 1) vmax = fmaxf(vmax, __shfl_xor(vmax, off));
    __shared__ float smax[4];
    int lane = threadIdx.x & 63, wid = threadIdx.x >> 6;
    if (lane == 0) smax[wid] = vmax;
    __syncthreads();
    if (threadIdx.x == 0)
        partials[blockIdx.x] = fmaxf(fmaxf(smax[0], smax[1]), fmaxf(smax[2], smax[3]));
}

__global__ void max_reduce_kernel(const float* __restrict__ partials,
                                  float* __restrict__ scale_out) {
    float v = 0.0f;
    for (int i = threadIdx.x; i < SOBEL_BLOCKS; i += 1024)
        v = fmaxf(v, partials[i]);
    #pragma unroll
    for (int off = 32; off; off >>= 1) v = fmaxf(v, __shfl_xor(v, off));
    __shared__ float smax[16];
    int lane = threadIdx.x & 63, wid = threadIdx.x >> 6;
    if (lane == 0) smax[wid] = v;
    __syncthreads();
    if (threadIdx.x == 0) {
        float m = smax[0];
        #pragma unroll
        for (int i = 1; i < 16; ++i) m = fmaxf(m, smax[i]);
        *scale_out = 1.0f / m;
    }
}

// In-place: mag -> E = exp(2*scale*mag), E in [1, e^2].
// Per tap: (tanh(scale*(mY-mX))+1)*0.5 == E_Y / (E_X + E_Y).
__global__ void prep_kernel(float4* __restrict__ mag4,
                            const float* __restrict__ scalep) {
    int id = blockIdx.x * blockDim.x + threadIdx.x;
    float k = 2.0f * (*scalep);
    float4 m = mag4[id];
    m.x = __expf(k * m.x);
    m.y = __expf(k * m.y);
    m.z = __expf(k * m.z);
    m.w = __expf(k * m.w);
    mag4[id] = m;
}

// ---- Fused V+H iteration v2: 64x32 tile; odd-pitch float planes ----
template <bool FINAL>
__global__ __launch_bounds__(TPB) void etf_fused(const float2* __restrict__ src,
                                                 float2* __restrict__ dstI,
                                                 float* __restrict__ dstP,
                                                 const float* __restrict__ E) {
    __shared__ float eT[ER][EP];    // 12.6 KB
    __shared__ float vx[TY][EP];    //  9.6 KB
    __shared__ float vy[TY][EP];    //  9.6 KB

    int bid = (int)blockIdx.x;
    int swz = (bid & 7) * (FBLK / 8) + (bid >> 3);   // 512 tiles = 1 image/XCD
    int img = swz >> 9;
    int cid = swz & 511;
    int tx = cid >> 5, ty = cid & 31;   // column-major: vertical neighbors adjacent
    int x0 = tx * TX, y0 = ty * TY;
    int base = img << 20;
    int t = threadIdx.x;
    int lane = t & 63, wave = t >> 6;

    // ---- stage E tile: rows [y0-5,y0+37), cols [x0-5,x0+69); wave-strided ----
    for (int r = wave; r < ER; r += 4) {
        int gy = y0 - MU + r;
        bool okr = (gy >= 0) && (gy < Hh);
        const float* erow = E + base + gy * Ww + (x0 - MU);
        {
            int cc = lane;
            int gx = x0 - MU + cc;
            bool ok = okr && (gx >= 0) && (gx < Ww);
            eT[r][cc] = ok ? erow[cc] : 1.0f;
        }
        if (lane < VW - 64) {
            int cc = 64 + lane;
            int gx = x0 - MU + cc;
            bool ok = okr && (gx < Ww);
            eT[r][cc] = ok ? erow[cc] : 1.0f;
        }
    }
    __syncthreads();

    // ---- V phase: 296 tasks = 74 cols x 4 groups of 8 rows ----
    #pragma unroll
    for (int round = 0; round < 2; ++round) {
        int T = t + round * TPB;
        if (T >= VW * 4) break;
        int g = T / VW;                 // const-div -> magic mul
        int c = T - g * VW;
        int gx = x0 - MU + c;
        int yb = y0 + g * 8;
        if (gx < 0 || gx >= Ww) {       // OOB col: taps contribute 0 in H
            #pragma unroll
            for (int k = 0; k < 8; ++k) { vx[g * 8 + k][c] = 0.0f; vy[g * 8 + k][c] = 0.0f; }
            continue;
        }
        float2 tt[18]; float ee[18];
        if (yb - MU >= 0 && yb + 13 <= Hh) {
            #pragma unroll
            for (int rr = 0; rr < 18; ++rr) {
                tt[rr] = src[base + (yb - MU + rr) * Ww + gx];
                ee[rr] = eT[g * 8 + rr][c];
            }
        } else {
            #pragma unroll
            for (int rr = 0; rr < 18; ++rr) {
                int row = yb - MU + rr;
                bool ok = (row >= 0) && (row < Hh);
                tt[rr] = ok ? src[base + row * Ww + gx] : make_float2(0.0f, 0.0f);
                ee[rr] = ok ? eT[g * 8 + rr][c] : 1.0f;
            }
        }
        #pragma unroll
        for (int k = 0; k < 8; ++k) {
            float2 tX = tt[k + MU];
            float  eX = ee[k + MU];
            float ax = 0.0f, ay = 0.0f;
            #pragma unroll
            for (int i = 0; i <= 2 * MU; ++i) {
                float2 tY = tt[k + i];
                float  eY = ee[k + i];
                float d = tX.x * tY.x + tX.y * tY.y;
                float w = eY * rcp_fast(eX + eY) * d;
                ax += tY.x * w;
                ay += tY.y * w;
            }
            vx[g * 8 + k][c] = ax;
            vy[g * 8 + k][c] = ay;
        }
    }
    __syncthreads();

    // ---- H phase: thread -> row r (0..31), 8-px col block cb ----
    int r = t >> 3;
    int cb = (t & 7) * 8;
    float wxv[18], wyv[18], we[18];
    #pragma unroll
    for (int q = 0; q < 18; ++q) {
        wxv[q] = vx[r][cb + q];
        wyv[q] = vy[r][cb + q];
        we[q]  = eT[r + MU][cb + q];
    }
    float ox[8], oy[8];
    #pragma unroll
    for (int j = 0; j < 8; ++j) {
        float txc = wxv[j + MU], tyc = wyv[j + MU];
        float eX = we[j + MU];
        float ax = 0.0f, ay = 0.0f;
        #pragma unroll
        for (int i = 0; i <= 2 * MU; ++i) {
            float vxt = wxv[j + i], vyt = wyv[j + i];
            float eY = we[j + i];
            float d = txc * vxt + tyc * vyt;
            float w = eY * rcp_fast(eX + eY) * d;
            ax += vxt * w;
            ay += vyt * w;
        }
        float n2 = ax * ax + ay * ay;
        float inv = (n2 > 0.0f) ? rsq_fast(n2) : 1.0f;
        ox[j] = ax * inv;
        oy[j] = ay * inv;
    }

    if (FINAL) {
        size_t p0 = ((size_t)(img * 2 + 0) << 20) + (size_t)(y0 + r) * Ww + x0 + cb;
        size_t p1 = ((size_t)(img * 2 + 1) << 20) + (size_t)(y0 + r) * Ww + x0 + cb;
        *(float4*)&dstP[p0]     = make_float4(ox[0], ox[1], ox[2], ox[3]);
        *(float4*)&dstP[p0 + 4] = make_float4(ox[4], ox[5], ox[6], ox[7]);
        *(float4*)&dstP[p1]     = make_float4(oy[0], oy[1], oy[2], oy[3]);
        *(float4*)&dstP[p1 + 4] = make_float4(oy[4], oy[5], oy[6], oy[7]);
    } else {
        // direct, fully-coalesced per 8-lane row group (512B contiguous)
        float4* dp = (float4*)&dstI[base + (y0 + r) * Ww + x0 + cb];
        dp[0] = make_float4(ox[0], oy[0], ox[1], oy[1]);
        dp[1] = make_float4(ox[2], oy[2], ox[3], oy[3]);
        dp[2] = make_float4(ox[4], oy[4], ox[5], oy[5]);
        dp[3] = make_float4(ox[6], oy[6], ox[7], oy[7]);
    }
}

extern "C" void kernel_launch(void* const* d_in, const int* in_sizes, int n_in,
                              void* d_out, int out_size, void* d_ws, size_t ws_size,
                              hipStream_t stream) {
    const float* in = (const float*)d_in[0];
    float* out = (float*)d_out;
    char* ws = (char*)d_ws;

    float* magE = (float*)ws;                                           // 32 MB
    float2* tA = (float2*)(ws + (size_t)NPIX * sizeof(float));          // 64 MB
    float* partials = (float*)(ws + (size_t)NPIX * sizeof(float)
                                  + (size_t)NPIX * sizeof(float2));
    float* scalep = partials + SOBEL_BLOCKS;
    float2* tOut = (float2*)out;

    sobel_kernel<<<SOBEL_BLOCKS, TPB, 0, stream>>>(in, tA, magE, partials);
    max_reduce_kernel<<<1, 1024, 0, stream>>>(partials, scalep);
    prep_kernel<<<NPIX / 4 / TPB, TPB, 0, stream>>>((float4*)magE, scalep);

    // iteration 1: tA -> tOut
    etf_fused<false><<<FBLK, TPB, 0, stream>>>(tA, tOut, nullptr, magE);
    // iteration 2: tOut -> tA
    etf_fused<false><<<FBLK, TPB, 0, stream>>>(tOut, tA, nullptr, magE);
    // iteration 3: tA -> out (planar)
    etf_fused<true ><<<FBLK, TPB, 0, stream>>>(tA, nullptr, out, magE);
}

// Round 10
// 234.074 us; speedup vs baseline: 1.2488x; 1.2488x over previous
//
#include <hip/hip_runtime.h>

#define MU 5
static constexpr int Hh = 1024, Ww = 1024, Bb = 8;
static constexpr int NPIX = Bb * Hh * Ww;
static constexpr int TPB = 256;
static constexpr int SOBEL_BLOCKS = NPIX / 4 / TPB;     // 8192 (4 px/thread)
static constexpr int PY = 8;                             // V: rows/thread
static constexpr int PXH = 4;                            // H: cols/thread
static constexpr int VBLK = NPIX / PY / TPB;             // 4096
static constexpr int HBLK = NPIX / PXH / TPB;            // 8192

__device__ __forceinline__ float rcp_fast(float x) { return __builtin_amdgcn_rcpf(x); }
__device__ __forceinline__ float rsq_fast(float x) { return __builtin_amdgcn_rsqf(x); }

// Bijective XCD-chunk swizzle (NB % 8 == 0): each XCD owns a contiguous
// chunk (= one image for VBLK, half an image for HBLK) -> halo reuse in L2.
template <int NB>
__device__ __forceinline__ int xcd_swizzle(int bid) {
    return (bid & 7) * (NB / 8) + (bid >> 3);
}

// ---- Sobel: 4 px per thread along a row; float4 + 2 edge scalars ----
__global__ __launch_bounds__(TPB) void sobel_kernel(
        const float* __restrict__ in, float2* __restrict__ tang,
        float* __restrict__ mag, float* __restrict__ partials) {
    int id = blockIdx.x * TPB + threadIdx.x;
    int xq = id & (Ww / 4 - 1);
    int x0 = xq * 4;
    int y  = (id >> 8) & (Hh - 1);
    int b  = id >> 18;
    const float* p = in + ((size_t)b << 20);

    float c[3][6];
    #pragma unroll
    for (int r = 0; r < 3; ++r) {
        int yy = y - 1 + r;
        bool okr = (yy >= 0) && (yy < Hh);
        const float* row = p + (okr ? yy : 0) * Ww;
        float4 v = okr ? *(const float4*)(row + x0) : make_float4(0.f, 0.f, 0.f, 0.f);
        c[r][1] = v.x; c[r][2] = v.y; c[r][3] = v.z; c[r][4] = v.w;
        c[r][0] = (okr && x0 > 0)      ? row[x0 - 1] : 0.0f;
        c[r][5] = (okr && x0 + 4 < Ww) ? row[x0 + 4] : 0.0f;
    }

    float S[6], D[6];
    #pragma unroll
    for (int cc = 0; cc < 6; ++cc) {
        S[cc] = c[0][cc] + 2.0f * c[1][cc] + c[2][cc];
        D[cc] = c[2][cc] - c[0][cc];
    }

    float2 tg[4];
    float  mg[4];
    float vmax = 0.0f;
    #pragma unroll
    for (int k = 0; k < 4; ++k) {
        float gx = S[k + 2] - S[k];
        float gy = D[k] + 2.0f * D[k + 1] + D[k + 2];
        float g2 = gx * gx + gy * gy;
        float irs = rsq_fast(g2);
        float m   = (g2 > 0.0f) ? g2 * irs : 0.0f;   // sqrt
        float inv = (g2 > 0.0f) ? irs : 1.0f;        // 1/sqrt
        mg[k] = m;
        tg[k] = make_float2(-gy * inv, gx * inv);
        vmax = fmaxf(vmax, m);
    }

    int idx = (b << 20) + y * Ww + x0;
    *(float4*)&mag[idx] = make_float4(mg[0], mg[1], mg[2], mg[3]);
    float4* tp = (float4*)&tang[idx];
    tp[0] = make_float4(tg[0].x, tg[0].y, tg[1].x, tg[1].y);
    tp[1] = make_float4(tg[2].x, tg[2].y, tg[3].x, tg[3].y);

    #pragma unroll
    for (int off = 32; off; off >>= 1) vmax = fmaxf(vmax, __shfl_xor(vmax, off));
    __shared__ float smax[4];
    int lane = threadIdx.x & 63, wid = threadIdx.x >> 6;
    if (lane == 0) smax[wid] = vmax;
    __syncthreads();
    if (threadIdx.x == 0)
        partials[blockIdx.x] = fmaxf(fmaxf(smax[0], smax[1]), fmaxf(smax[2], smax[3]));
}

__global__ void max_reduce_kernel(const float* __restrict__ partials,
                                  float* __restrict__ scale_out) {
    float v = 0.0f;
    for (int i = threadIdx.x; i < SOBEL_BLOCKS; i += 1024)
        v = fmaxf(v, partials[i]);
    #pragma unroll
    for (int off = 32; off; off >>= 1) v = fmaxf(v, __shfl_xor(v, off));
    __shared__ float smax[16];
    int lane = threadIdx.x & 63, wid = threadIdx.x >> 6;
    if (lane == 0) smax[wid] = v;
    __syncthreads();
    if (threadIdx.x == 0) {
        float m = smax[0];
        #pragma unroll
        for (int i = 1; i < 16; ++i) m = fmaxf(m, smax[i]);
        *scale_out = 1.0f / m;
    }
}

// In-place: mag -> E = exp(2*scale*mag), E in [1, e^2].
// Per tap: (tanh(scale*(mY-mX))+1)*0.5 == E_Y / (E_X + E_Y).
__global__ void prep_kernel(float4* __restrict__ mag4,
                            const float* __restrict__ scalep) {
    int id = blockIdx.x * blockDim.x + threadIdx.x;
    float k = 2.0f * (*scalep);
    float4 m = mag4[id];
    m.x = __expf(k * m.x);
    m.y = __expf(k * m.y);
    m.z = __expf(k * m.z);
    m.w = __expf(k * m.w);
    mag4[id] = m;
}

// ---- V pass: PY=8 vertically-consecutive outputs per thread ----
__global__ __launch_bounds__(TPB) void etf_v(const float2* __restrict__ src,
                                             float2* __restrict__ dst,
                                             const float* __restrict__ E) {
    int bid = xcd_swizzle<VBLK>((int)blockIdx.x);
    int gid = bid * TPB + threadIdx.x;
    int x = gid & (Ww - 1);
    int yg = (gid >> 10) & (Hh / PY - 1);
    int b = gid >> 17;
    int y0 = yg * PY;
    int base = b << 20;

    float2 t[PY + 10];
    float  e[PY + 10];
    if (yg >= 1 && yg <= Hh / PY - 2) {          // uniform per block
        #pragma unroll
        for (int r = 0; r < PY + 10; ++r) {
            int j = base + (y0 - MU + r) * Ww + x;
            t[r] = src[j];
            e[r] = E[j];
        }
    } else {
        #pragma unroll
        for (int r = 0; r < PY + 10; ++r) {
            int row = y0 - MU + r;
            bool ok = (row >= 0) && (row < Hh);
            int j = base + (ok ? row : 0) * Ww + x;
            t[r] = ok ? src[j] : make_float2(0.0f, 0.0f);
            e[r] = ok ? E[j] : 1.0f;             // d=0 anyway; keep rcp finite
        }
    }

    #pragma unroll
    for (int k = 0; k < PY; ++k) {
        float2 tX = t[k + MU];
        float  eX = e[k + MU];
        float ax = 0.0f, ay = 0.0f;
        #pragma unroll
        for (int i = 0; i <= 2 * MU; ++i) {
            float2 tY = t[k + i];
            float  eY = e[k + i];
            float d = tX.x * tY.x + tX.y * tY.y;
            float w = eY * rcp_fast(eX + eY) * d;
            ax += tY.x * w;
            ay += tY.y * w;
        }
        dst[base + (y0 + k) * Ww + x] = make_float2(ax, ay);
    }
}

// ---- H pass: PXH=4 outputs per thread (R3 structure: 22 us; PX=8 was 40) ----
template <bool FINAL>
__global__ __launch_bounds__(TPB) void etf_h(const float2* __restrict__ src,
                                             float2* __restrict__ dstI,
                                             float* __restrict__ dstP,
                                             const float* __restrict__ E) {
    int bid = xcd_swizzle<HBLK>((int)blockIdx.x);
    int gid = bid * TPB + threadIdx.x;
    int xq = gid & (Ww / PXH - 1);       // 0..255
    int x0 = xq * PXH;
    int y = (gid >> 8) & (Hh - 1);
    int b = gid >> 18;
    int rowbase = (b << 20) + y * Ww;

    float2 t[PXH + 10];
    float  e[PXH + 10];
    if (xq >= 2 && xq <= Ww / PXH - 3) { // interior (x0-5 >= 0, x0+8 <= 1023)
        #pragma unroll
        for (int r = 0; r < PXH + 10; ++r) {
            int j = rowbase + x0 - MU + r;
            t[r] = src[j];
            e[r] = E[j];
        }
    } else {                             // border: masked scalar path
        #pragma unroll
        for (int r = 0; r < PXH + 10; ++r) {
            int col = x0 - MU + r;
            bool ok = (col >= 0) && (col < Ww);
            int j = rowbase + (ok ? col : 0);
            t[r] = ok ? src[j] : make_float2(0.0f, 0.0f);
            e[r] = ok ? E[j] : 1.0f;
        }
    }

    float ox[PXH], oy[PXH];
    #pragma unroll
    for (int k = 0; k < PXH; ++k) {
        float2 tX = t[k + MU];
        float  eX = e[k + MU];
        float ax = 0.0f, ay = 0.0f;
        #pragma unroll
        for (int i = 0; i <= 2 * MU; ++i) {
            float2 tY = t[k + i];
            float  eY = e[k + i];
            float d = tX.x * tY.x + tX.y * tY.y;
            float w = eY * rcp_fast(eX + eY) * d;
            ax += tY.x * w;
            ay += tY.y * w;
        }
        float n2 = ax * ax + ay * ay;
        float inv = (n2 > 0.0f) ? rsq_fast(n2) : 1.0f;
        ox[k] = ax * inv;
        oy[k] = ay * inv;
    }

    if (FINAL) {
        *(float4*)&dstP[((size_t)(b * 2 + 0) << 20) + y * Ww + x0] =
            make_float4(ox[0], ox[1], ox[2], ox[3]);
        *(float4*)&dstP[((size_t)(b * 2 + 1) << 20) + y * Ww + x0] =
            make_float4(oy[0], oy[1], oy[2], oy[3]);
    } else {
        float4* dp = (float4*)&dstI[rowbase + x0];
        dp[0] = make_float4(ox[0], oy[0], ox[1], oy[1]);
        dp[1] = make_float4(ox[2], oy[2], ox[3], oy[3]);
    }
}

extern "C" void kernel_launch(void* const* d_in, const int* in_sizes, int n_in,
                              void* d_out, int out_size, void* d_ws, size_t ws_size,
                              hipStream_t stream) {
    const float* in = (const float*)d_in[0];
    float* out = (float*)d_out;
    char* ws = (char*)d_ws;

    float* magE = (float*)ws;                                           // 32 MB
    float2* tA = (float2*)(ws + (size_t)NPIX * sizeof(float));          // 64 MB
    float* partials = (float*)(ws + (size_t)NPIX * sizeof(float)
                                  + (size_t)NPIX * sizeof(float2));
    float* scalep = partials + SOBEL_BLOCKS;
    float2* tOut = (float2*)out;

    sobel_kernel<<<SOBEL_BLOCKS, TPB, 0, stream>>>(in, tOut, magE, partials);
    max_reduce_kernel<<<1, 1024, 0, stream>>>(partials, scalep);
    prep_kernel<<<NPIX / 4 / TPB, TPB, 0, stream>>>((float4*)magE, scalep);

    // iteration 1
    etf_v<<<VBLK, TPB, 0, stream>>>(tOut, tA, magE);
    etf_h<false><<<HBLK, TPB, 0, stream>>>(tA, tOut, nullptr, magE);
    // iteration 2
    etf_v<<<VBLK, TPB, 0, stream>>>(tOut, tA, magE);
    etf_h<false><<<HBLK, TPB, 0, stream>>>(tA, tOut, nullptr, magE);
    // iteration 3
    etf_v<<<VBLK, TPB, 0, stream>>>(tOut, tA, magE);
    etf_h<true ><<<HBLK, TPB, 0, stream>>>(tA, nullptr, out, magE);
}